// Round 14
// baseline (198.391 us; speedup 1.0000x reference)
//
#include <hip/hip_runtime.h>

// GlobalAttentionPooling: tensor_square_0e -> selu -> @W -> segment softmax -> weighted segment sum
// N nodes, 80 f32 ft (32 scalar + 16 x 3-vec), NG=1024 graphs (sorted batch_index), F=664.
//
// Math identities (validated rounds 1-4, absmax 3.9e-3):
//   selu const term cancels in softmax; pre-scale s by sqrt(log2e), v by sqrt(log2e/sqrt3)
//   so pair products are f*log2e -> exp2 directly. out_g = (sum nf*ex)/z_g.
//
// Round-19 == Round-18 resubmitted (container failed twice; no data, hypothesis untested).
//   2 NODES PER THREAD (keep r16 pair-split). r17 showed resident waves/CU pinned ~12-15
//   across ALL configs -> TLP lever saturated. Remaining lever: per-wave efficiency.
//   Sharing W ds_read + row index across two adjacent nodes: ds_reads/node 344 -> 104,
//   staging loads/node 40 -> 20, ILP-2 chains hide exp2/LDS latency inside the wave.
//   s2A+s2B pinned (64 regs) + 16 acc ~ 80 peak, bounds(256,4) cap 128; vector halves
//   per-node to cap vp pressure.
//   Falsifiers: WRITE>35MB = spill; VGPR~40 = pins collapsed; main>=72 clean = stall not
//   memory-shaped -> structural floor.

typedef float f2 __attribute__((ext_vector_type(2)));

#define C0 32
#define C1 16
#define NODE_F 80
#define NG_CONST 1024
#define NPB 256                 // nodes per block (2 per thread)
#define TPB 256
#define NCHUNK 12               // phase-2 node chunks (NCHUNK*20 <= TPB)

#define SELU_SCALE 1.0507009873554804934193349852946
#define SELU_ALPHA 1.6732632423543772848170429916717
#define LOG2E      1.4426950408889634073599246810019

#define CS_SCALE 1.2011224087864498f    // sqrt(log2e)
#define CV_SCALE 0.91271231102878545f   // sqrt(log2e/sqrt(3))

// ws float layout:
//   [0, 81920)        S accum: [1024 graphs][80 ch]
//   [81920, 82944)    z accum: [1024]
//   [82944, 84224)    Wpad: 512 f2 scalar rows (32x16) then 128 f2 vec rows (16x8)
#define WS_S 0
#define WS_Z 81920
#define WS_W 82944

__device__ __forceinline__ int ks_idx(int i, int j) { return i * C0 - (i * (i - 1)) / 2 + (j - i); }
__device__ __forceinline__ int kv_idx(int i, int j) { return 528 + i * C1 - (i * (i - 1)) / 2 + (j - i); }

// zero the accumulators + build padded W tables (r16 layout: stride 16 f2 / 8 f2)
__global__ __launch_bounds__(256) void prep_kernel(
    const float* __restrict__ W, float* __restrict__ ws)
{
    const int t = blockIdx.x * blockDim.x + threadIdx.x;
    if (t < 82944) {
        ws[t] = 0.0f;                       // S and z
    } else {
        int u = t - 82944;
        if (u < 512) {                      // Ws: i in [0,32), q in [0,16)
            int i = u >> 4, q = u & 15;
            int j0 = 2 * q, j1 = 2 * q + 1;
            ws[WS_W + 2 * u]     = (j0 >= i) ? W[ks_idx(i, j0)] : 0.0f;
            ws[WS_W + 2 * u + 1] = (j1 >= i) ? W[ks_idx(i, j1)] : 0.0f;
        } else if (u < 640) {               // Wv: i in [0,16), q in [0,8)
            int v = u - 512;
            int i = v >> 3, q = v & 7;
            int j0 = 2 * q, j1 = 2 * q + 1;
            ws[WS_W + 1024 + 2 * v]     = (j0 >= i) ? W[kv_idx(i, j0)] : 0.0f;
            ws[WS_W + 1024 + 2 * v + 1] = (j1 >= i) ? W[kv_idx(i, j1)] : 0.0f;
        }
    }
}

__global__ __launch_bounds__(TPB, 4) void main_kernel(
    const float* __restrict__ nf, const int* __restrict__ bi,
    const float* __restrict__ ws, float* __restrict__ S,
    float* __restrict__ z, int N)
{
    __shared__ __align__(16) float Wlds[1280];
    __shared__ float exl[NPB];
    __shared__ int   bil[NPB];

    const int tid  = threadIdx.x;
    const int base = blockIdx.x * NPB;
    const float4* g4 = (const float4*)nf;

    #pragma unroll
    for (int u = tid; u < 1280; u += TPB) Wlds[u] = ws[WS_W + u];

    {
        int idx = base + tid;
        bil[tid] = bi[idx > N - 1 ? N - 1 : idx];
    }

    const int  m      = tid >> 1;           // node pair 0..127
    const int  p      = tid & 1;            // parity: rows i with (i&1)==p
    const int  nA     = base + 2 * m;
    const int  nB     = nA + 1;
    const bool validA = (nA < N);
    const bool validB = (nB < N);
    const int  nnA    = validA ? nA : (N - 1);
    const int  nnB    = validB ? nB : (N - 1);
    __syncthreads();                        // Wlds + bil ready

    const float4* gpA = g4 + (size_t)nnA * 20;
    const float4* gpB = g4 + (size_t)nnB * 20;
    const f2* WsL = (const f2*)Wlds;          // 512 f2
    const f2* WvL = (const f2*)(Wlds + 1024); // 128 f2

    // ---- stage both nodes' scalar halves -> s2A/s2B, PINNED ----
    f2 s2A[C0 / 2], s2B[C0 / 2];
    {
        float4 rs[8];
        #pragma unroll
        for (int q = 0; q < 8; ++q) rs[q] = gpA[q];
        #pragma unroll
        for (int q = 0; q < 8; ++q) {
            s2A[2 * q]     = f2{rs[q].x, rs[q].y} * CS_SCALE;
            s2A[2 * q + 1] = f2{rs[q].z, rs[q].w} * CS_SCALE;
        }
    }
    #pragma unroll
    for (int q = 0; q < C0 / 2; ++q) asm volatile("" : "+v"(s2A[q]));
    {
        float4 rs[8];
        #pragma unroll
        for (int q = 0; q < 8; ++q) rs[q] = gpB[q];
        #pragma unroll
        for (int q = 0; q < 8; ++q) {
            s2B[2 * q]     = f2{rs[q].x, rs[q].y} * CS_SCALE;
            s2B[2 * q + 1] = f2{rs[q].z, rs[q].w} * CS_SCALE;
        }
    }
    #pragma unroll
    for (int q = 0; q < C0 / 2; ++q) asm volatile("" : "+v"(s2B[q]));

    // accumulators: [linear|exp] x [node A|B] x 2 interleave
    f2 aLA[2], aEA[2], aLB[2], aEB[2];
    aLA[0] = (f2)0.f; aLA[1] = (f2)0.f; aEA[0] = (f2)0.f; aEA[1] = (f2)0.f;
    aLB[0] = (f2)0.f; aLB[1] = (f2)0.f; aEB[0] = (f2)0.f; aEB[1] = (f2)0.f;

    // scalar triangle: rows i = 2k+p, k=0..15; ONE ds_read serves both nodes (136 iters)
    #pragma unroll
    for (int k = 0; k < C0 / 2; ++k) {
        const int i = 2 * k + p;
        const float siA = p ? s2A[k].y : s2A[k].x;
        const float siB = p ? s2B[k].y : s2B[k].x;
        const f2 siA2 = f2{siA, siA};
        const f2 siB2 = f2{siB, siB};
        #pragma unroll
        for (int q = k; q < C0 / 2; ++q) {
            const f2 w = WsL[i * 16 + q];       // shared: 2 addrs/wave, 2-way = free
            f2 fa = siA2 * s2A[q];
            f2 fb = siB2 * s2B[q];
            f2 pa = __builtin_elementwise_max(fa, (f2)0.f);
            f2 pb = __builtin_elementwise_max(fb, (f2)0.f);
            f2 ma = __builtin_elementwise_min(fa, (f2)0.f);
            f2 mb = __builtin_elementwise_min(fb, (f2)0.f);
            f2 ea; ea.x = __builtin_amdgcn_exp2f(ma.x);
                   ea.y = __builtin_amdgcn_exp2f(ma.y);
            f2 eb; eb.x = __builtin_amdgcn_exp2f(mb.x);
                   eb.y = __builtin_amdgcn_exp2f(mb.y);
            aLA[q & 1] = __builtin_elementwise_fma(w, pa, aLA[q & 1]);
            aEA[q & 1] = __builtin_elementwise_fma(w, ea, aEA[q & 1]);
            aLB[q & 1] = __builtin_elementwise_fma(w, pb, aLB[q & 1]);
            aEB[q & 1] = __builtin_elementwise_fma(w, eb, aEB[q & 1]);
        }
    }

    // ---- vector part, node A then node B (keeps vp pressure to one node) ----
    #pragma unroll
    for (int nb2 = 0; nb2 < 2; ++nb2) {
        const float4* gp = nb2 ? gpB : gpA;
        float4 rv[12];
        #pragma unroll
        for (int q = 0; q < 12; ++q) rv[q] = gp[8 + q];
        f2 vp[C1 / 2][3];
        {
            const float* rvf = (const float*)rv;
            #pragma unroll
            for (int q = 0; q < C1 / 2; ++q) {
                #pragma unroll
                for (int c = 0; c < 3; ++c)
                    vp[q][c] = f2{rvf[6 * q + c], rvf[6 * q + 3 + c]} * CV_SCALE;
            }
        }
        #pragma unroll
        for (int k = 0; k < C1 / 2; ++k) {
            const int i = 2 * k + p;
            const float vi0 = p ? vp[k][0].y : vp[k][0].x;
            const float vi1 = p ? vp[k][1].y : vp[k][1].x;
            const float vi2 = p ? vp[k][2].y : vp[k][2].x;
            #pragma unroll
            for (int q = k; q < C1 / 2; ++q) {
                f2 f = vp[q][0] * f2{vi0, vi0};
                f = __builtin_elementwise_fma(vp[q][1], f2{vi1, vi1}, f);
                f = __builtin_elementwise_fma(vp[q][2], f2{vi2, vi2}, f);
                f2 pp = __builtin_elementwise_max(f, (f2)0.f);
                f2 mm = __builtin_elementwise_min(f, (f2)0.f);
                f2 e; e.x = __builtin_amdgcn_exp2f(mm.x);
                      e.y = __builtin_amdgcn_exp2f(mm.y);
                f2 w = WvL[i * 8 + q];
                if (nb2) {
                    aLB[q & 1] = __builtin_elementwise_fma(w, pp, aLB[q & 1]);
                    aEB[q & 1] = __builtin_elementwise_fma(w, e, aEB[q & 1]);
                } else {
                    aLA[q & 1] = __builtin_elementwise_fma(w, pp, aLA[q & 1]);
                    aEA[q & 1] = __builtin_elementwise_fma(w, e, aEA[q & 1]);
                }
            }
        }
    }

    float A1a = aLA[0].x + aLA[0].y + aLA[1].x + aLA[1].y;
    float A2a = aEA[0].x + aEA[0].y + aEA[1].x + aEA[1].y;
    float A1b = aLB[0].x + aLB[0].y + aLB[1].x + aLB[1].y;
    float A2b = aEB[0].x + aEB[0].y + aEB[1].x + aEB[1].y;
    A1a += __shfl_xor(A1a, 1);  A2a += __shfl_xor(A2a, 1);   // combine parity halves
    A1b += __shfl_xor(A1b, 1);  A2b += __shfl_xor(A2b, 1);
    if (p == 0) {
        const float l2a = fmaf((float)SELU_SCALE, A1a,
                               (float)(SELU_SCALE * SELU_ALPHA * LOG2E) * A2a);
        const float l2b = fmaf((float)SELU_SCALE, A1b,
                               (float)(SELU_SCALE * SELU_ALPHA * LOG2E) * A2b);
        exl[2 * m]     = validA ? __builtin_amdgcn_exp2f(l2a) : 0.0f;
        exl[2 * m + 1] = validB ? __builtin_amdgcn_exp2f(l2b) : 0.0f;
    }
    __syncthreads();

    // ---- phase 2 (tid<240): 12 chunks x 20 cols, ~21 nodes each, flush per graph run ----
    if (tid < NCHUNK * 20) {
        const int no = tid / 20;       // 0..11
        const int c4 = tid % 20;
        const int nb = (no * NPB) / NCHUNK;
        const int ne = ((no + 1) * NPB) / NCHUNK;
        int cg = bil[nb];
        float4 acc = make_float4(0.f, 0.f, 0.f, 0.f);
        float  zacc = 0.0f;

        for (int nl = nb; nl < ne; ++nl) {
            const int g2 = bil[nl];
            if (g2 != cg) {
                unsafeAtomicAdd(&S[cg * NODE_F + c4 * 4 + 0], acc.x);
                unsafeAtomicAdd(&S[cg * NODE_F + c4 * 4 + 1], acc.y);
                unsafeAtomicAdd(&S[cg * NODE_F + c4 * 4 + 2], acc.z);
                unsafeAtomicAdd(&S[cg * NODE_F + c4 * 4 + 3], acc.w);
                if (c4 == 0) unsafeAtomicAdd(&z[cg], zacc);
                acc = make_float4(0.f, 0.f, 0.f, 0.f); zacc = 0.0f; cg = g2;
            }
            int idx = base + nl; if (idx > N - 1) idx = N - 1;   // pad nodes have w=0
            const float  w = exl[nl];
            const float4 v = g4[(size_t)idx * 20 + c4];
            acc.x = fmaf(v.x, w, acc.x); acc.y = fmaf(v.y, w, acc.y);
            acc.z = fmaf(v.z, w, acc.z); acc.w = fmaf(v.w, w, acc.w);
            zacc += w;
        }
        unsafeAtomicAdd(&S[cg * NODE_F + c4 * 4 + 0], acc.x);
        unsafeAtomicAdd(&S[cg * NODE_F + c4 * 4 + 1], acc.y);
        unsafeAtomicAdd(&S[cg * NODE_F + c4 * 4 + 2], acc.z);
        unsafeAtomicAdd(&S[cg * NODE_F + c4 * 4 + 3], acc.w);
        if (c4 == 0) unsafeAtomicAdd(&z[cg], zacc);
    }
}

__global__ __launch_bounds__(256) void divide_kernel(
    const float* __restrict__ S, const float* __restrict__ z,
    float* __restrict__ out)
{
    const int t = blockIdx.x * blockDim.x + threadIdx.x;
    if (t >= NG_CONST * NODE_F) return;
    const float zz = z[t / NODE_F];
    out[t] = (zz > 0.0f) ? (S[t] / zz) : 0.0f;
}

extern "C" void kernel_launch(void* const* d_in, const int* in_sizes, int n_in,
                              void* d_out, int out_size, void* d_ws, size_t ws_size,
                              hipStream_t stream) {
    const float* nf = (const float*)d_in[0];   // (N, 80) f32
    const int*   bi = (const int*)d_in[1];     // (N,) i32 sorted
    // d_in[2] = num_graphs (static 1024)
    const float* W  = (const float*)d_in[3];   // (664,) f32
    float* out = (float*)d_out;

    const int N = in_sizes[0] / NODE_F;
    float* ws = (float*)d_ws;
    float* S  = ws + WS_S;
    float* z  = ws + WS_Z;

    hipLaunchKernelGGL(prep_kernel, dim3(332), dim3(256), 0, stream, W, ws);
    hipLaunchKernelGGL(main_kernel, dim3((N + NPB - 1) / NPB), dim3(TPB), 0, stream,
                       nf, bi, ws, S, z, N);
    hipLaunchKernelGGL(divide_kernel, dim3((NG_CONST * NODE_F + 255) / 256), dim3(256),
                       0, stream, S, z, out);
}